// Round 20
// baseline (144.065 us; speedup 1.0000x reference)
//
#include <hip/hip_runtime.h>

typedef float f32x4 __attribute__((ext_vector_type(4)));
typedef __bf16 bf16x8 __attribute__((ext_vector_type(8)));
typedef unsigned short u16x8 __attribute__((ext_vector_type(8)));
typedef unsigned short u16x4 __attribute__((ext_vector_type(4)));

#define MFMA16(a, b, c) __builtin_amdgcn_mfma_f32_16x16x32_bf16((a), (b), (c), 0, 0, 0)

__device__ __forceinline__ unsigned short f2bf(float f) {
    __bf16 h = (__bf16)f;  // RNE
    union { __bf16 h; unsigned short u; } c; c.h = h;
    return c.u;
}

__device__ __forceinline__ void gload_lds16(const unsigned short* g, unsigned short* l) {
    __builtin_amdgcn_global_load_lds(
        (const __attribute__((address_space(1))) unsigned int*)g,
        (__attribute__((address_space(3))) unsigned int*)l, 16, 0, 0);
}

// ------- merged weight transposes: fp32 [R][C] -> bf16 [C][R], two segments -----
__global__ void k_prep(const float* __restrict__ Wa, unsigned short* __restrict__ WaT,
                       const float* __restrict__ Wp, unsigned short* __restrict__ WpT) {
    __shared__ unsigned short tile[32][33];
    const int seg = (blockIdx.x < 72) ? 0 : 1;
    const float* in = seg ? Wp : Wa;
    unsigned short* out = seg ? WpT : WaT;
    const int C = seg ? 768 : 2304;
    const int bx = (seg ? (blockIdx.x - 72) : blockIdx.x) * 32;
    const int by = blockIdx.y * 32;
    const int tx = threadIdx.x;
    const int ty = threadIdx.y;
    #pragma unroll
    for (int i = ty; i < 32; i += 8)
        tile[i][tx] = f2bf(in[(size_t)(by + i) * C + bx + tx]);
    __syncthreads();
    #pragma unroll
    for (int i = ty; i < 32; i += 8)
        out[(size_t)(bx + i) * 768 + by + tx] = tile[tx][i];
}

// ------- QKV GEMM: 256x128 block, 512 thr, BK=64, dbuf, FUSED fp32->bf16 A ------
// A read DIRECTLY as fp32 (convert pass deleted). Per tile: issue B(t+1)
// gload_lds + A(t+1) float4 loads BEFORE compute(t); cvt + swizzled
// ds_write_b128 AFTER compute (full phase of slack, T14); barrier.
// bn 0-5: Q (pre-scaled 0.125*log2e), 6-11: K, 12-17: V sigma-permuted-transposed.
__global__ __launch_bounds__(512) void k_gemm_qkv(
    const float* __restrict__ Ax,
    const unsigned short* __restrict__ Bt,
    const float* __restrict__ bias,
    unsigned short* __restrict__ Qo,
    unsigned short* __restrict__ Ko,
    unsigned short* __restrict__ Vto)
{
    __shared__ unsigned short SM[2 * 16384 + 2 * 8192];  // A[2] 64KB | B[2] 32KB
    const int nwg = gridDim.x * gridDim.y;               // 576
    const int bid0 = blockIdx.y * gridDim.x + blockIdx.x;
    const int logical = (bid0 & 7) * (nwg >> 3) + (bid0 >> 3);
    const int bm = logical / gridDim.x;
    const int bn = logical % gridDim.x;
    const int tid = threadIdx.x;
    const int w = tid >> 6, l = tid & 63;
    const int wm = w >> 1, wn = w & 1;
    const int ln = l & 15, kb = l >> 4;

    f32x4 acc[4][4];
    #pragma unroll
    for (int i = 0; i < 4; ++i)
        #pragma unroll
        for (int j = 0; j < 4; ++j)
            #pragma unroll
            for (int r = 0; r < 4; ++r) acc[i][j][r] = 0.f;

    const float* Ab = Ax + (size_t)(bm * 256) * 768;
    const unsigned short* Bb = Bt + (size_t)(bn * 128) * 768;

    const int srow = tid >> 3;    // 0..63
    const int sslot = tid & 7;
    const int csw = (sslot ^ (srow & 7)) * 8;           // B source-side swizzle
    const int ac = tid & 7;                              // A col-chunk (8 elems)
    const int ascol = (ac ^ (srow & 7)) * 8;            // A swizzled write slot

    float4 av[4][2];

    #define ALOAD(t_)                                                               \
        {                                                                           \
            const int k0_ = (t_) * 64 + ac * 8;                                     \
            _Pragma("unroll")                                                       \
            for (int j = 0; j < 4; ++j) {                                           \
                const float* p = &Ab[(size_t)(j * 64 + srow) * 768 + k0_];          \
                av[j][0] = *reinterpret_cast<const float4*>(p);                     \
                av[j][1] = *reinterpret_cast<const float4*>(p + 4);                 \
            }                                                                       \
        }

    #define AWRITE(buf_)                                                            \
        {                                                                           \
            _Pragma("unroll")                                                       \
            for (int j = 0; j < 4; ++j) {                                           \
                u16x8 o;                                                            \
                o[0] = f2bf(av[j][0].x); o[1] = f2bf(av[j][0].y);                   \
                o[2] = f2bf(av[j][0].z); o[3] = f2bf(av[j][0].w);                   \
                o[4] = f2bf(av[j][1].x); o[5] = f2bf(av[j][1].y);                   \
                o[6] = f2bf(av[j][1].z); o[7] = f2bf(av[j][1].w);                   \
                *reinterpret_cast<u16x8*>(                                          \
                    &SM[(buf_) * 16384 + (j * 64 + srow) * 64 + ascol]) = o;        \
            }                                                                       \
        }

    #define BSTAGE(t_, buf_)                                                        \
        {                                                                           \
            const int k0_ = (t_) * 64;                                              \
            _Pragma("unroll")                                                       \
            for (int j = 0; j < 2; ++j) {                                           \
                const int r = j * 64 + srow;                                        \
                gload_lds16(&Bb[(size_t)r * 768 + k0_ + csw],                       \
                            &SM[32768 + (buf_) * 8192 + r * 64 + sslot * 8]);       \
            }                                                                       \
        }

    // prologue
    BSTAGE(0, 0);
    ALOAD(0);
    AWRITE(0);
    __syncthreads();

    for (int t = 0; t < 12; ++t) {
        const int buf = t & 1;
        if (t + 1 < 12) {
            BSTAGE(t + 1, buf ^ 1);
            ALOAD(t + 1);
        }
        #pragma unroll
        for (int kh = 0; kh < 2; ++kh) {
            bf16x8 af[4], bfr[4];
            #pragma unroll
            for (int mt = 0; mt < 4; ++mt) {
                const int row = wm * 64 + mt * 16 + ln;
                const int slot = ((kh << 2) | kb) ^ (row & 7);
                af[mt] = *reinterpret_cast<const bf16x8*>(
                    &SM[buf * 16384 + row * 64 + slot * 8]);
            }
            #pragma unroll
            for (int nt = 0; nt < 4; ++nt) {
                const int row = wn * 64 + nt * 16 + ln;
                const int slot = ((kh << 2) | kb) ^ (row & 7);
                bfr[nt] = *reinterpret_cast<const bf16x8*>(
                    &SM[32768 + buf * 8192 + row * 64 + slot * 8]);
            }
            #pragma unroll
            for (int mt = 0; mt < 4; ++mt)
                #pragma unroll
                for (int nt = 0; nt < 4; ++nt)
                    acc[mt][nt] = MFMA16(af[mt], bfr[nt], acc[mt][nt]);
        }
        if (t + 1 < 12) AWRITE(buf ^ 1);   // loads had a full compute phase of slack
        __syncthreads();
    }

    const float SC = 0.1803368801111204f;  // 0.125 * log2(e)

    if (bn >= 12) {
        // V section: two 128-row halves through LDS transpose, then coalesced
        // stores into Vt with sigma key-permutation.
        unsigned short* Ts = SM;  // 128(col) x 128(row-half), 32 KB
        const int cl_w = wn * 64;
        #pragma unroll
        for (int hh2 = 0; hh2 < 2; ++hh2) {
            if ((wm >> 1) == hh2) {
                #pragma unroll
                for (int mt = 0; mt < 4; ++mt) {
                    #pragma unroll
                    for (int nt = 0; nt < 4; ++nt) {
                        const int cl = cl_w + nt * 16 + ln;
                        const float bv = bias[bn * 128 + cl];
                        #pragma unroll
                        for (int r = 0; r < 4; ++r) {
                            const int rl = (wm & 1) * 64 + mt * 16 + kb * 4 + r;  // 0..127
                            const int pos = cl * 128 + ((((rl >> 3) ^ (cl & 7)) << 3) | (rl & 7));
                            Ts[pos] = f2bf(acc[mt][nt][r] + bv);
                        }
                    }
                }
            }
            __syncthreads();
            {
                const int cl = tid >> 2;
                const int col = bn * 128 + cl;
                const int cc = col - 1536;
                const int hh = cc >> 6, dd = cc & 63;
                #pragma unroll
                for (int j8 = 0; j8 < 4; ++j8) {
                    const int rb = (tid & 3) * 4 + j8;
                    u16x8 val = *reinterpret_cast<const u16x8*>(&Ts[cl * 128 + ((rb ^ (cl & 7)) << 3)]);
                    const int tg = bm * 256 + hh2 * 128 + rb * 8;
                    const int bb = tg >> 11;
                    const int tloc = tg & 2047;
                    const int grp = tloc & ~31;
                    const int jj = (tloc >> 3) & 3;
                    const int tlo = grp + 8 * ((2 * jj) & 3) + 4 * (jj >> 1);
                    const int thi = grp + 8 * ((2 * jj + 1) & 3) + 4 * (jj >> 1);
                    unsigned short* basep = &Vto[((size_t)((bb * 12 + hh) * 64 + dd)) * 2048];
                    *reinterpret_cast<u16x4*>(basep + tlo) =
                        __builtin_shufflevector(val, val, 0, 1, 2, 3);
                    *reinterpret_cast<u16x4*>(basep + thi) =
                        __builtin_shufflevector(val, val, 4, 5, 6, 7);
                }
            }
            __syncthreads();
        }
        return;
    }

    #pragma unroll
    for (int mt = 0; mt < 4; ++mt) {
        #pragma unroll
        for (int nt = 0; nt < 4; ++nt) {
            const int col = bn * 128 + wn * 64 + nt * 16 + ln;
            #pragma unroll
            for (int r = 0; r < 4; ++r) {
                const int row = bm * 256 + wm * 64 + mt * 16 + kb * 4 + r;
                float v = acc[mt][nt][r] + bias[col];
                int cc = col >= 768 ? col - 768 : col;
                int h = cc >> 6, d = cc & 63;
                int b = row >> 11, t = row & 2047;
                if (col < 768)
                    Qo[((size_t)((b * 12 + h) * 2048 + t)) * 64 + d] = f2bf(v * SC);
                else
                    Ko[((size_t)((b * 12 + h) * 2048 + t)) * 64 + d] = f2bf(v);
            }
        }
    }
    #undef ALOAD
    #undef AWRITE
    #undef BSTAGE
}

// ------- proj GEMM: R16 proven config — 128x128 block, 256 thr, BK=64, 1-buf ----
__global__ __launch_bounds__(256) void k_gemm_proj(
    const unsigned short* __restrict__ A,
    const unsigned short* __restrict__ Bt,
    const float* __restrict__ bias,
    float* __restrict__ Co,
    int K)
{
    constexpr int BM = 128;
    __shared__ unsigned short SM[(BM + 128) * 64];
    unsigned short* As = SM;
    unsigned short* Bs = SM + BM * 64;
    const int nwg = gridDim.x * gridDim.y;
    const int bid0 = blockIdx.y * gridDim.x + blockIdx.x;
    const int logical = (bid0 & 7) * (nwg >> 3) + (bid0 >> 3);
    const int bm = logical / gridDim.x;
    const int bn = logical % gridDim.x;
    const int tid = threadIdx.x;
    const int w = tid >> 6, l = tid & 63;
    const int wm = w >> 1, wn = w & 1;
    const int ln = l & 15, kb = l >> 4;

    f32x4 acc[4][4];
    #pragma unroll
    for (int i = 0; i < 4; ++i)
        #pragma unroll
        for (int j = 0; j < 4; ++j)
            #pragma unroll
            for (int r = 0; r < 4; ++r) acc[i][j][r] = 0.f;

    const unsigned short* Ab = A + (size_t)(bm * BM) * K;
    const unsigned short* Bb = Bt + (size_t)(bn * 128) * K;

    const int srow = tid >> 3;
    const int sslot = tid & 7;
    const int csw = (sslot ^ (srow & 7)) * 8;

    for (int k0 = 0; k0 < K; k0 += 64) {
        #pragma unroll
        for (int j = 0; j < 4; ++j) {
            const int r = j * 32 + srow;
            gload_lds16(&Ab[(size_t)r * K + k0 + csw], &As[r * 64 + sslot * 8]);
        }
        #pragma unroll
        for (int j = 0; j < 4; ++j) {
            const int r = j * 32 + srow;
            gload_lds16(&Bb[(size_t)r * K + k0 + csw], &Bs[r * 64 + sslot * 8]);
        }
        __syncthreads();
        #pragma unroll
        for (int kh = 0; kh < 2; ++kh) {
            bf16x8 af[4], bfr[4];
            #pragma unroll
            for (int mt = 0; mt < 4; ++mt) {
                const int row = wm * 64 + mt * 16 + ln;
                const int slot = ((kh << 2) | kb) ^ (row & 7);
                af[mt] = *reinterpret_cast<const bf16x8*>(&As[row * 64 + slot * 8]);
            }
            #pragma unroll
            for (int nt = 0; nt < 4; ++nt) {
                const int row = wn * 64 + nt * 16 + ln;
                const int slot = ((kh << 2) | kb) ^ (row & 7);
                bfr[nt] = *reinterpret_cast<const bf16x8*>(&Bs[row * 64 + slot * 8]);
            }
            #pragma unroll
            for (int mt = 0; mt < 4; ++mt)
                #pragma unroll
                for (int nt = 0; nt < 4; ++nt)
                    acc[mt][nt] = MFMA16(af[mt], bfr[nt], acc[mt][nt]);
        }
        __syncthreads();
    }

    #pragma unroll
    for (int mt = 0; mt < 4; ++mt) {
        #pragma unroll
        for (int nt = 0; nt < 4; ++nt) {
            const int col = bn * 128 + wn * 64 + nt * 16 + ln;
            #pragma unroll
            for (int r = 0; r < 4; ++r) {
                const int row = bm * BM + wm * 64 + mt * 16 + kb * 4 + r;
                Co[(size_t)row * 768 + col] = acc[mt][nt][r] + bias[col];
            }
        }
    }
}

// ---- flash attention v13: R14 winner, unchanged ---------------------------------
__global__ __launch_bounds__(256) void k_attn(
    const unsigned short* __restrict__ Q,   // [BH][T][64] (pre-scaled)
    const unsigned short* __restrict__ Kk,  // [BH][T][64]
    const unsigned short* __restrict__ Vt,  // [BH][64][T'] (sigma-permuted keys)
    unsigned short* __restrict__ Oo)        // [B][T][768] bf16
{
    __shared__ unsigned short SMEM[4 * 4096];  // Ks0|Ks1|Vs0|Vs1 (32KB)
    const int bid0 = blockIdx.x;
    const int xcd = bid0 & 7;
    const int loc = bid0 >> 3;
    const int qb = 15 - (loc / 6);
    const int bh = xcd * 6 + (loc % 6);
    const int tid = threadIdx.x;
    const int w = tid >> 6, l = tid & 63;
    const int ln = l & 15, kb = l >> 4;
    const int kbq = kb * 4;
    const int b = bh / 12, h = bh - b * 12;
    const int q0w = qb * 128 + w * 32;

    const unsigned short* Qb = Q + (size_t)bh * 2048 * 64;
    const unsigned short* Kb = Kk + (size_t)bh * 2048 * 64;
    const unsigned short* Vb = Vt + (size_t)bh * 64 * 2048;

    bf16x8 qf[2][2];
    #pragma unroll
    for (int qn = 0; qn < 2; ++qn) {
        const unsigned short* qr = &Qb[(size_t)(q0w + qn * 16 + ln) * 64 + kb * 8];
        qf[qn][0] = *reinterpret_cast<const bf16x8*>(qr);
        qf[qn][1] = *reinterpret_cast<const bf16x8*>(qr + 32);
    }

    bf16x8 vones;
    #pragma unroll
    for (int e = 0; e < 8; ++e) vones[e] = (__bf16)1.0f;
    const f32x4 fzero = {0.f, 0.f, 0.f, 0.f};

    f32x4 oaccT[2][4];
    f32x4 den[2];
    #pragma unroll
    for (int qn = 0; qn < 2; ++qn) {
        #pragma unroll
        for (int r = 0; r < 4; ++r) den[qn][r] = 0.f;
        #pragma unroll
        for (int dt = 0; dt < 4; ++dt)
            #pragma unroll
            for (int r = 0; r < 4; ++r) oaccT[qn][dt][r] = 0.f;
    }

    const int lb = ln & 7;
    const int aR0 = ln * 64 + (kb ^ lb) * 8;
    const int aR1 = ln * 64 + ((4 | kb) ^ lb) * 8;

    const int srow = tid >> 3;
    const int sslot = tid & 7;
    const int csw = (sslot ^ (srow & 7)) * 8;
    const int lastkt = (q0w + 31) >> 6;

    #define STAGE(kt_, buf_)                                                        \
        {                                                                           \
            const int kb_ = (kt_) * 64;                                             \
            _Pragma("unroll")                                                       \
            for (int j = 0; j < 2; ++j) {                                           \
                const int r = j * 32 + srow;                                        \
                gload_lds16(&Kb[(size_t)(kb_ + r) * 64 + csw],                      \
                            &SMEM[(buf_) * 4096 + r * 64 + sslot * 8]);             \
                gload_lds16(&Vb[(size_t)r * 2048 + kb_ + csw],                      \
                            &SMEM[8192 + (buf_) * 4096 + r * 64 + sslot * 8]);      \
            }                                                                       \
        }

    #define COMPUTE(kt_, BUF)                                                       \
        if ((kt_) <= lastkt) {                                                      \
            bf16x8 kf[4][2];                                                        \
            _Pragma("unroll")                                                       \
            for (int km = 0; km < 4; ++km) {                                        \
                kf[km][0] = *reinterpret_cast<const bf16x8*>(                       \
                    &SMEM[(BUF) * 4096 + km * 1024 + aR0]);                         \
                kf[km][1] = *reinterpret_cast<const bf16x8*>(                       \
                    &SMEM[(BUF) * 4096 + km * 1024 + aR1]);                         \
            }                                                                       \
            f32x4 st[4][2];                                                         \
            _Pragma("unroll")                                                       \
            for (int km = 0; km < 4; ++km)                                          \
                _Pragma("unroll")                                                   \
                for (int qn = 0; qn < 2; ++qn) {                                    \
                    st[km][qn] = MFMA16(kf[km][0], qf[qn][0], fzero);               \
                    st[km][qn] = MFMA16(kf[km][1], qf[qn][1], st[km][qn]);          \
                }                                                                   \
            bf16x8 vf[4][2];                                                        \
            _Pragma("unroll")                                                       \
            for (int dt = 0; dt < 4; ++dt) {                                        \
                vf[dt][0] = *reinterpret_cast<const bf16x8*>(                       \
                    &SMEM[8192 + (BUF) * 4096 + dt * 1024 + aR0]);                  \
                vf[dt][1] = *reinterpret_cast<const bf16x8*>(                       \
                    &SMEM[8192 + (BUF) * 4096 + dt * 1024 + aR1]);                  \
            }                                                                       \
            if ((kt_) == lastkt) {                                                  \
                const int kbase_ = (kt_) * 64;                                      \
                _Pragma("unroll")                                                   \
                for (int qn = 0; qn < 2; ++qn) {                                    \
                    const int qrow = q0w + qn * 16 + ln;                            \
                    _Pragma("unroll")                                               \
                    for (int km = 0; km < 4; ++km)                                  \
                        _Pragma("unroll")                                           \
                        for (int r = 0; r < 4; ++r) {                               \
                            float sv = st[km][qn][r];                               \
                            const int key = kbase_ + km * 16 + kbq + r;             \
                            sv = (key <= qrow) ? sv : -1e30f;                       \
                            st[km][qn][r] = __builtin_amdgcn_exp2f(sv);             \
                        }                                                           \
                }                                                                   \
            } else {                                                                \
                _Pragma("unroll")                                                   \
                for (int qn = 0; qn < 2; ++qn)                                      \
                    _Pragma("unroll")                                               \
                    for (int km = 0; km < 4; ++km)                                  \
                        _Pragma("unroll")                                           \
                        for (int r = 0; r < 4; ++r)                                 \
                            st[km][qn][r] =                                         \
                                __builtin_amdgcn_exp2f(st[km][qn][r]);              \
            }                                                                       \
            bf16x8 pa[2][2];                                                        \
            _Pragma("unroll")                                                       \
            for (int qn = 0; qn < 2; ++qn)                                          \
                _Pragma("unroll")                                                   \
                for (int kh = 0; kh < 2; ++kh) {                                    \
                    bf16x8 t;                                                       \
                    _Pragma("unroll")                                               \
                    for (int r = 0; r < 4; ++r) {                                   \
                        t[r]     = (__bf16)st[2 * kh][qn][r];                       \
                        t[r + 4] = (__bf16)st[2 * kh + 1][qn][r];                   \
                    }                                                               \
                    pa[qn][kh] = t;                                                 \
                }                                                                   \
            _Pragma("unroll")                                                       \
            for (int qn = 0; qn < 2; ++qn) {                                        \
                _Pragma("unroll")                                                   \
                for (int dt = 0; dt < 4; ++dt) {                                    \
                    oaccT[qn][dt] = MFMA16(pa[qn][0], vf[dt][0], oaccT[qn][dt]);    \
                    oaccT[qn][dt] = MFMA16(pa[qn][1], vf[dt][1], oaccT[qn][dt]);    \
                }                                                                   \
                den[qn] = MFMA16(pa[qn][0], vones, den[qn]);                        \
                den[qn] = MFMA16(pa[qn][1], vones, den[qn]);                        \
            }                                                                       \
        }

    STAGE(0, 0);

    for (int s = 0; s <= qb; ++s) {
        const int ktA = 2 * s;
        const int ktB = 2 * s + 1;
        __syncthreads();
        STAGE(ktB, 1);
        COMPUTE(ktA, 0);
        __syncthreads();
        if (s < qb) STAGE(ktA + 2, 0);
        COMPUTE(ktB, 1);
    }

    #pragma unroll
    for (int qn = 0; qn < 2; ++qn) {
        #pragma unroll
        for (int r = 0; r < 4; ++r) {
            const float inv = 1.0f / den[qn][r];
            const int t = q0w + qn * 16 + kbq + r;
            #pragma unroll
            for (int dt = 0; dt < 4; ++dt)
                Oo[((size_t)(b * 2048 + t)) * 768 + h * 64 + dt * 16 + ln] =
                    f2bf(oaccT[qn][dt][r] * inv);
        }
    }
    #undef STAGE
    #undef COMPUTE
}

extern "C" void kernel_launch(void* const* d_in, const int* in_sizes, int n_in,
                              void* d_out, int out_size, void* d_ws, size_t ws_size,
                              hipStream_t stream) {
    const float* x      = (const float*)d_in[0];
    const float* W_attn = (const float*)d_in[1];
    const float* b_attn = (const float*)d_in[2];
    const float* W_proj = (const float*)d_in[3];
    const float* b_proj = (const float*)d_in[4];
    float* out = (float*)d_out;

    char* ws = (char*)d_ws;
    const size_t SZ_AO = (size_t)8192 * 768 * 2;      // attn output (bf16)
    const size_t SZ_WA = (size_t)2304 * 768 * 2;
    const size_t SZ_WP = (size_t)768 * 768 * 2;
    const size_t SZ_T  = (size_t)8192 * 768 * 2;

    unsigned short* attn_o = (unsigned short*)(ws);
    unsigned short* wa_t = (unsigned short*)(ws + SZ_AO);
    unsigned short* wp_t = (unsigned short*)(ws + SZ_AO + SZ_WA);
    unsigned short* Qb   = (unsigned short*)(ws + SZ_AO + SZ_WA + SZ_WP);
    unsigned short* Kb   = (unsigned short*)(ws + SZ_AO + SZ_WA + SZ_WP + SZ_T);
    unsigned short* Vtb  = (unsigned short*)(ws + SZ_AO + SZ_WA + SZ_WP + 2 * SZ_T);

    k_prep<<<dim3(96, 24), dim3(32, 8), 0, stream>>>(W_attn, wa_t, W_proj, wp_t);
    k_gemm_qkv<<<dim3(18, 32), 512, 0, stream>>>(x, wa_t, b_attn, Qb, Kb, Vtb);
    k_attn<<<768, 256, 0, stream>>>(Qb, Kb, Vtb, attn_o);
    k_gemm_proj<<<dim3(6, 64), 256, 0, stream>>>(attn_o, wp_t, b_proj, out, 768);
}

// Round 21
// 114.086 us; speedup vs baseline: 1.2628x; 1.2628x over previous
//
#include <hip/hip_runtime.h>

typedef float f32x4 __attribute__((ext_vector_type(4)));
typedef __bf16 bf16x8 __attribute__((ext_vector_type(8)));
typedef unsigned short u16x8 __attribute__((ext_vector_type(8)));
typedef unsigned short u16x4 __attribute__((ext_vector_type(4)));

#define MFMA16(a, b, c) __builtin_amdgcn_mfma_f32_16x16x32_bf16((a), (b), (c), 0, 0, 0)

__device__ __forceinline__ unsigned short f2bf(float f) {
    __bf16 h = (__bf16)f;  // RNE
    union { __bf16 h; unsigned short u; } c; c.h = h;
    return c.u;
}

__device__ __forceinline__ void gload_lds16(const unsigned short* g, unsigned short* l) {
    __builtin_amdgcn_global_load_lds(
        (const __attribute__((address_space(1))) unsigned int*)g,
        (__attribute__((address_space(3))) unsigned int*)l, 16, 0, 0);
}

// ---- prep: weight transposes (fp32 [R][C] -> bf16 [C][R]) + x fp32->bf16 -------
// Three grid segments in ONE launch: bx<72 Wa-transpose, 72<=bx<96 Wp-transpose,
// bx>=96 convert chunk (256 thr x 4 elems). Saves two launch gaps.
__global__ void k_prepconv(const float* __restrict__ x, unsigned short* __restrict__ xb,
                           const float* __restrict__ Wa, unsigned short* __restrict__ WaT,
                           const float* __restrict__ Wp, unsigned short* __restrict__ WpT) {
    __shared__ unsigned short tile[32][33];
    const int bx = blockIdx.x, by = blockIdx.y;
    const int tx = threadIdx.x, ty = threadIdx.y;
    if (bx >= 96) {
        const int idx = (bx - 96) * 24 + by;       // 0..6143
        const int i = (idx * 256 + ty * 32 + tx) * 4;
        float4 v = *reinterpret_cast<const float4*>(x + i);
        ushort4 o;
        o.x = f2bf(v.x); o.y = f2bf(v.y); o.z = f2bf(v.z); o.w = f2bf(v.w);
        *reinterpret_cast<ushort4*>(xb + i) = o;
        return;
    }
    const int seg = (bx < 72) ? 0 : 1;
    const float* in = seg ? Wp : Wa;
    unsigned short* out = seg ? WpT : WaT;
    const int C = seg ? 768 : 2304;
    const int bx0 = (seg ? (bx - 72) : bx) * 32;
    const int by0 = by * 32;
    #pragma unroll
    for (int i = ty; i < 32; i += 8)
        tile[i][tx] = f2bf(in[(size_t)(by0 + i) * C + bx0 + tx]);
    __syncthreads();
    #pragma unroll
    for (int i = ty; i < 32; i += 8)
        out[(size_t)(bx0 + i) * 768 + by0 + tx] = tile[tx][i];
}

// ------- QKV GEMM: R16 proven config — 256x128, 512 thr, BK=64, single-buffer ---
// (Measured best of 5 structures: 47.9us. dbuf/3-deep/fused-A all failed to beat.)
// bn 0-5: Q (pre-scaled 0.125*log2e), 6-11: K, 12-17: V sigma-permuted-transposed.
__global__ __launch_bounds__(512) void k_gemm_qkv(
    const unsigned short* __restrict__ A,
    const unsigned short* __restrict__ Bt,
    const float* __restrict__ bias,
    unsigned short* __restrict__ Qo,
    unsigned short* __restrict__ Ko,
    unsigned short* __restrict__ Vto,
    int K)
{
    __shared__ unsigned short SM[(256 + 128) * 64];  // As(32KB) | Bs(16KB); As reused as Ts
    unsigned short* As = SM;
    unsigned short* Bs = SM + 256 * 64;
    const int nwg = gridDim.x * gridDim.y;
    const int bid0 = blockIdx.y * gridDim.x + blockIdx.x;
    const int logical = (bid0 & 7) * (nwg >> 3) + (bid0 >> 3);
    const int bm = logical / gridDim.x;
    const int bn = logical % gridDim.x;
    const int tid = threadIdx.x;
    const int w = tid >> 6, l = tid & 63;
    const int wm = w >> 1, wn = w & 1;
    const int ln = l & 15, kb = l >> 4;

    f32x4 acc[4][4];
    #pragma unroll
    for (int i = 0; i < 4; ++i)
        #pragma unroll
        for (int j = 0; j < 4; ++j)
            #pragma unroll
            for (int r = 0; r < 4; ++r) acc[i][j][r] = 0.f;

    const unsigned short* Ab = A + (size_t)(bm * 256) * K;
    const unsigned short* Bb = Bt + (size_t)(bn * 128) * K;

    const int srow = tid >> 3;   // 0..63
    const int sslot = tid & 7;
    const int csw = (sslot ^ (srow & 7)) * 8;

    for (int k0 = 0; k0 < K; k0 += 64) {
        #pragma unroll
        for (int j = 0; j < 4; ++j) {
            const int r = j * 64 + srow;
            gload_lds16(&Ab[(size_t)r * K + k0 + csw], &As[r * 64 + sslot * 8]);
        }
        #pragma unroll
        for (int j = 0; j < 2; ++j) {
            const int r = j * 64 + srow;
            gload_lds16(&Bb[(size_t)r * K + k0 + csw], &Bs[r * 64 + sslot * 8]);
        }
        __syncthreads();
        #pragma unroll
        for (int kh = 0; kh < 2; ++kh) {
            bf16x8 af[4], bfr[4];
            #pragma unroll
            for (int mt = 0; mt < 4; ++mt) {
                const int row = wm * 64 + mt * 16 + ln;
                const int slot = ((kh << 2) | kb) ^ (row & 7);
                af[mt] = *reinterpret_cast<const bf16x8*>(&As[row * 64 + slot * 8]);
            }
            #pragma unroll
            for (int nt = 0; nt < 4; ++nt) {
                const int row = wn * 64 + nt * 16 + ln;
                const int slot = ((kh << 2) | kb) ^ (row & 7);
                bfr[nt] = *reinterpret_cast<const bf16x8*>(&Bs[row * 64 + slot * 8]);
            }
            #pragma unroll
            for (int mt = 0; mt < 4; ++mt)
                #pragma unroll
                for (int nt = 0; nt < 4; ++nt)
                    acc[mt][nt] = MFMA16(af[mt], bfr[nt], acc[mt][nt]);
        }
        __syncthreads();
    }

    const float SC = 0.1803368801111204f;  // 0.125 * log2(e)

    if (bn >= 12) {
        // V section: two 128-row halves through LDS transpose (Ts = SM region),
        // then coalesced stores into Vt with sigma key-permutation.
        unsigned short* Ts = SM;  // 128(col) x 128(row-half)
        const int cl_w = wn * 64;
        #pragma unroll
        for (int hh2 = 0; hh2 < 2; ++hh2) {
            if ((wm >> 1) == hh2) {
                #pragma unroll
                for (int mt = 0; mt < 4; ++mt) {
                    #pragma unroll
                    for (int nt = 0; nt < 4; ++nt) {
                        const int cl = cl_w + nt * 16 + ln;
                        const float bv = bias[bn * 128 + cl];
                        #pragma unroll
                        for (int r = 0; r < 4; ++r) {
                            const int rl = (wm & 1) * 64 + mt * 16 + kb * 4 + r;  // 0..127
                            const int pos = cl * 128 + ((((rl >> 3) ^ (cl & 7)) << 3) | (rl & 7));
                            Ts[pos] = f2bf(acc[mt][nt][r] + bv);
                        }
                    }
                }
            }
            __syncthreads();
            {
                const int cl = tid >> 2;
                const int col = bn * 128 + cl;
                const int cc = col - 1536;
                const int hh = cc >> 6, dd = cc & 63;
                #pragma unroll
                for (int j8 = 0; j8 < 4; ++j8) {
                    const int rb = (tid & 3) * 4 + j8;
                    u16x8 val = *reinterpret_cast<const u16x8*>(&Ts[cl * 128 + ((rb ^ (cl & 7)) << 3)]);
                    const int tg = bm * 256 + hh2 * 128 + rb * 8;
                    const int bb = tg >> 11;
                    const int tloc = tg & 2047;
                    const int grp = tloc & ~31;
                    const int jj = (tloc >> 3) & 3;
                    const int tlo = grp + 8 * ((2 * jj) & 3) + 4 * (jj >> 1);
                    const int thi = grp + 8 * ((2 * jj + 1) & 3) + 4 * (jj >> 1);
                    unsigned short* basep = &Vto[((size_t)((bb * 12 + hh) * 64 + dd)) * 2048];
                    *reinterpret_cast<u16x4*>(basep + tlo) =
                        __builtin_shufflevector(val, val, 0, 1, 2, 3);
                    *reinterpret_cast<u16x4*>(basep + thi) =
                        __builtin_shufflevector(val, val, 4, 5, 6, 7);
                }
            }
            __syncthreads();
        }
        return;
    }

    #pragma unroll
    for (int mt = 0; mt < 4; ++mt) {
        #pragma unroll
        for (int nt = 0; nt < 4; ++nt) {
            const int col = bn * 128 + wn * 64 + nt * 16 + ln;
            #pragma unroll
            for (int r = 0; r < 4; ++r) {
                const int row = bm * 256 + wm * 64 + mt * 16 + kb * 4 + r;
                float v = acc[mt][nt][r] + bias[col];
                int cc = col >= 768 ? col - 768 : col;
                int h = cc >> 6, d = cc & 63;
                int b = row >> 11, t = row & 2047;
                if (col < 768)
                    Qo[((size_t)((b * 12 + h) * 2048 + t)) * 64 + d] = f2bf(v * SC);
                else
                    Ko[((size_t)((b * 12 + h) * 2048 + t)) * 64 + d] = f2bf(v);
            }
        }
    }
}

// ------- proj GEMM: R16 proven config — 128x128 block, 256 thr, BK=64, 1-buf ----
__global__ __launch_bounds__(256) void k_gemm_proj(
    const unsigned short* __restrict__ A,
    const unsigned short* __restrict__ Bt,
    const float* __restrict__ bias,
    float* __restrict__ Co,
    int K)
{
    constexpr int BM = 128;
    __shared__ unsigned short SM[(BM + 128) * 64];
    unsigned short* As = SM;
    unsigned short* Bs = SM + BM * 64;
    const int nwg = gridDim.x * gridDim.y;
    const int bid0 = blockIdx.y * gridDim.x + blockIdx.x;
    const int logical = (bid0 & 7) * (nwg >> 3) + (bid0 >> 3);
    const int bm = logical / gridDim.x;
    const int bn = logical % gridDim.x;
    const int tid = threadIdx.x;
    const int w = tid >> 6, l = tid & 63;
    const int wm = w >> 1, wn = w & 1;
    const int ln = l & 15, kb = l >> 4;

    f32x4 acc[4][4];
    #pragma unroll
    for (int i = 0; i < 4; ++i)
        #pragma unroll
        for (int j = 0; j < 4; ++j)
            #pragma unroll
            for (int r = 0; r < 4; ++r) acc[i][j][r] = 0.f;

    const unsigned short* Ab = A + (size_t)(bm * BM) * K;
    const unsigned short* Bb = Bt + (size_t)(bn * 128) * K;

    const int srow = tid >> 3;
    const int sslot = tid & 7;
    const int csw = (sslot ^ (srow & 7)) * 8;

    for (int k0 = 0; k0 < K; k0 += 64) {
        #pragma unroll
        for (int j = 0; j < 4; ++j) {
            const int r = j * 32 + srow;
            gload_lds16(&Ab[(size_t)r * K + k0 + csw], &As[r * 64 + sslot * 8]);
        }
        #pragma unroll
        for (int j = 0; j < 4; ++j) {
            const int r = j * 32 + srow;
            gload_lds16(&Bb[(size_t)r * K + k0 + csw], &Bs[r * 64 + sslot * 8]);
        }
        __syncthreads();
        #pragma unroll
        for (int kh = 0; kh < 2; ++kh) {
            bf16x8 af[4], bfr[4];
            #pragma unroll
            for (int mt = 0; mt < 4; ++mt) {
                const int row = wm * 64 + mt * 16 + ln;
                const int slot = ((kh << 2) | kb) ^ (row & 7);
                af[mt] = *reinterpret_cast<const bf16x8*>(&As[row * 64 + slot * 8]);
            }
            #pragma unroll
            for (int nt = 0; nt < 4; ++nt) {
                const int row = wn * 64 + nt * 16 + ln;
                const int slot = ((kh << 2) | kb) ^ (row & 7);
                bfr[nt] = *reinterpret_cast<const bf16x8*>(&Bs[row * 64 + slot * 8]);
            }
            #pragma unroll
            for (int mt = 0; mt < 4; ++mt)
                #pragma unroll
                for (int nt = 0; nt < 4; ++nt)
                    acc[mt][nt] = MFMA16(af[mt], bfr[nt], acc[mt][nt]);
        }
        __syncthreads();
    }

    #pragma unroll
    for (int mt = 0; mt < 4; ++mt) {
        #pragma unroll
        for (int nt = 0; nt < 4; ++nt) {
            const int col = bn * 128 + wn * 64 + nt * 16 + ln;
            #pragma unroll
            for (int r = 0; r < 4; ++r) {
                const int row = bm * BM + wm * 64 + mt * 16 + kb * 4 + r;
                Co[(size_t)row * 768 + col] = acc[mt][nt][r] + bias[col];
            }
        }
    }
}

// ---- flash attention v13: R14 winner, unchanged ---------------------------------
__global__ __launch_bounds__(256) void k_attn(
    const unsigned short* __restrict__ Q,   // [BH][T][64] (pre-scaled)
    const unsigned short* __restrict__ Kk,  // [BH][T][64]
    const unsigned short* __restrict__ Vt,  // [BH][64][T'] (sigma-permuted keys)
    unsigned short* __restrict__ Oo)        // [B][T][768] bf16
{
    __shared__ unsigned short SMEM[4 * 4096];  // Ks0|Ks1|Vs0|Vs1 (32KB)
    const int bid0 = blockIdx.x;
    const int xcd = bid0 & 7;
    const int loc = bid0 >> 3;
    const int qb = 15 - (loc / 6);
    const int bh = xcd * 6 + (loc % 6);
    const int tid = threadIdx.x;
    const int w = tid >> 6, l = tid & 63;
    const int ln = l & 15, kb = l >> 4;
    const int kbq = kb * 4;
    const int b = bh / 12, h = bh - b * 12;
    const int q0w = qb * 128 + w * 32;

    const unsigned short* Qb = Q + (size_t)bh * 2048 * 64;
    const unsigned short* Kb = Kk + (size_t)bh * 2048 * 64;
    const unsigned short* Vb = Vt + (size_t)bh * 64 * 2048;

    bf16x8 qf[2][2];
    #pragma unroll
    for (int qn = 0; qn < 2; ++qn) {
        const unsigned short* qr = &Qb[(size_t)(q0w + qn * 16 + ln) * 64 + kb * 8];
        qf[qn][0] = *reinterpret_cast<const bf16x8*>(qr);
        qf[qn][1] = *reinterpret_cast<const bf16x8*>(qr + 32);
    }

    bf16x8 vones;
    #pragma unroll
    for (int e = 0; e < 8; ++e) vones[e] = (__bf16)1.0f;
    const f32x4 fzero = {0.f, 0.f, 0.f, 0.f};

    f32x4 oaccT[2][4];
    f32x4 den[2];
    #pragma unroll
    for (int qn = 0; qn < 2; ++qn) {
        #pragma unroll
        for (int r = 0; r < 4; ++r) den[qn][r] = 0.f;
        #pragma unroll
        for (int dt = 0; dt < 4; ++dt)
            #pragma unroll
            for (int r = 0; r < 4; ++r) oaccT[qn][dt][r] = 0.f;
    }

    const int lb = ln & 7;
    const int aR0 = ln * 64 + (kb ^ lb) * 8;
    const int aR1 = ln * 64 + ((4 | kb) ^ lb) * 8;

    const int srow = tid >> 3;
    const int sslot = tid & 7;
    const int csw = (sslot ^ (srow & 7)) * 8;
    const int lastkt = (q0w + 31) >> 6;

    #define STAGE(kt_, buf_)                                                        \
        {                                                                           \
            const int kb_ = (kt_) * 64;                                             \
            _Pragma("unroll")                                                       \
            for (int j = 0; j < 2; ++j) {                                           \
                const int r = j * 32 + srow;                                        \
                gload_lds16(&Kb[(size_t)(kb_ + r) * 64 + csw],                      \
                            &SMEM[(buf_) * 4096 + r * 64 + sslot * 8]);             \
                gload_lds16(&Vb[(size_t)r * 2048 + kb_ + csw],                      \
                            &SMEM[8192 + (buf_) * 4096 + r * 64 + sslot * 8]);      \
            }                                                                       \
        }

    #define COMPUTE(kt_, BUF)                                                       \
        if ((kt_) <= lastkt) {                                                      \
            bf16x8 kf[4][2];                                                        \
            _Pragma("unroll")                                                       \
            for (int km = 0; km < 4; ++km) {                                        \
                kf[km][0] = *reinterpret_cast<const bf16x8*>(                       \
                    &SMEM[(BUF) * 4096 + km * 1024 + aR0]);                         \
                kf[km][1] = *reinterpret_cast<const bf16x8*>(                       \
                    &SMEM[(BUF) * 4096 + km * 1024 + aR1]);                         \
            }                                                                       \
            f32x4 st[4][2];                                                         \
            _Pragma("unroll")                                                       \
            for (int km = 0; km < 4; ++km)                                          \
                _Pragma("unroll")                                                   \
                for (int qn = 0; qn < 2; ++qn) {                                    \
                    st[km][qn] = MFMA16(kf[km][0], qf[qn][0], fzero);               \
                    st[km][qn] = MFMA16(kf[km][1], qf[qn][1], st[km][qn]);          \
                }                                                                   \
            bf16x8 vf[4][2];                                                        \
            _Pragma("unroll")                                                       \
            for (int dt = 0; dt < 4; ++dt) {                                        \
                vf[dt][0] = *reinterpret_cast<const bf16x8*>(                       \
                    &SMEM[8192 + (BUF) * 4096 + dt * 1024 + aR0]);                  \
                vf[dt][1] = *reinterpret_cast<const bf16x8*>(                       \
                    &SMEM[8192 + (BUF) * 4096 + dt * 1024 + aR1]);                  \
            }                                                                       \
            if ((kt_) == lastkt) {                                                  \
                const int kbase_ = (kt_) * 64;                                      \
                _Pragma("unroll")                                                   \
                for (int qn = 0; qn < 2; ++qn) {                                    \
                    const int qrow = q0w + qn * 16 + ln;                            \
                    _Pragma("unroll")                                               \
                    for (int km = 0; km < 4; ++km)                                  \
                        _Pragma("unroll")                                           \
                        for (int r = 0; r < 4; ++r) {                               \
                            float sv = st[km][qn][r];                               \
                            const int key = kbase_ + km * 16 + kbq + r;             \
                            sv = (key <= qrow) ? sv : -1e30f;                       \
                            st[km][qn][r] = __builtin_amdgcn_exp2f(sv);             \
                        }                                                           \
                }                                                                   \
            } else {                                                                \
                _Pragma("unroll")                                                   \
                for (int qn = 0; qn < 2; ++qn)                                      \
                    _Pragma("unroll")                                               \
                    for (int km = 0; km < 4; ++km)                                  \
                        _Pragma("unroll")                                           \
                        for (int r = 0; r < 4; ++r)                                 \
                            st[km][qn][r] =                                         \
                                __builtin_amdgcn_exp2f(st[km][qn][r]);              \
            }                                                                       \
            bf16x8 pa[2][2];                                                        \
            _Pragma("unroll")                                                       \
            for (int qn = 0; qn < 2; ++qn)                                          \
                _Pragma("unroll")                                                   \
                for (int kh = 0; kh < 2; ++kh) {                                    \
                    bf16x8 t;                                                       \
                    _Pragma("unroll")                                               \
                    for (int r = 0; r < 4; ++r) {                                   \
                        t[r]     = (__bf16)st[2 * kh][qn][r];                       \
                        t[r + 4] = (__bf16)st[2 * kh + 1][qn][r];                   \
                    }                                                               \
                    pa[qn][kh] = t;                                                 \
                }                                                                   \
            _Pragma("unroll")                                                       \
            for (int qn = 0; qn < 2; ++qn) {                                        \
                _Pragma("unroll")                                                   \
                for (int dt = 0; dt < 4; ++dt) {                                    \
                    oaccT[qn][dt] = MFMA16(pa[qn][0], vf[dt][0], oaccT[qn][dt]);    \
                    oaccT[qn][dt] = MFMA16(pa[qn][1], vf[dt][1], oaccT[qn][dt]);    \
                }                                                                   \
                den[qn] = MFMA16(pa[qn][0], vones, den[qn]);                        \
                den[qn] = MFMA16(pa[qn][1], vones, den[qn]);                        \
            }                                                                       \
        }

    STAGE(0, 0);

    for (int s = 0; s <= qb; ++s) {
        const int ktA = 2 * s;
        const int ktB = 2 * s + 1;
        __syncthreads();
        STAGE(ktB, 1);
        COMPUTE(ktA, 0);
        __syncthreads();
        if (s < qb) STAGE(ktA + 2, 0);
        COMPUTE(ktB, 1);
    }

    #pragma unroll
    for (int qn = 0; qn < 2; ++qn) {
        #pragma unroll
        for (int r = 0; r < 4; ++r) {
            const float inv = 1.0f / den[qn][r];
            const int t = q0w + qn * 16 + kbq + r;
            #pragma unroll
            for (int dt = 0; dt < 4; ++dt)
                Oo[((size_t)(b * 2048 + t)) * 768 + h * 64 + dt * 16 + ln] =
                    f2bf(oaccT[qn][dt][r] * inv);
        }
    }
    #undef STAGE
    #undef COMPUTE
}

extern "C" void kernel_launch(void* const* d_in, const int* in_sizes, int n_in,
                              void* d_out, int out_size, void* d_ws, size_t ws_size,
                              hipStream_t stream) {
    const float* x      = (const float*)d_in[0];
    const float* W_attn = (const float*)d_in[1];
    const float* b_attn = (const float*)d_in[2];
    const float* W_proj = (const float*)d_in[3];
    const float* b_proj = (const float*)d_in[4];
    float* out = (float*)d_out;

    char* ws = (char*)d_ws;
    const size_t SZ_X  = (size_t)8192 * 768 * 2;
    const size_t SZ_WA = (size_t)2304 * 768 * 2;
    const size_t SZ_WP = (size_t)768 * 768 * 2;
    const size_t SZ_T  = (size_t)8192 * 768 * 2;

    unsigned short* x_bf = (unsigned short*)(ws);
    unsigned short* wa_t = (unsigned short*)(ws + SZ_X);
    unsigned short* wp_t = (unsigned short*)(ws + SZ_X + SZ_WA);
    unsigned short* Qb   = (unsigned short*)(ws + SZ_X + SZ_WA + SZ_WP);
    unsigned short* Kb   = (unsigned short*)(ws + SZ_X + SZ_WA + SZ_WP + SZ_T);
    unsigned short* Vtb  = (unsigned short*)(ws + SZ_X + SZ_WA + SZ_WP + 2 * SZ_T);
    unsigned short* attn_o = x_bf;  // x_bf dead after QKV GEMM; reuse

    k_prepconv<<<dim3(96 + 256, 24), dim3(32, 8), 0, stream>>>(x, x_bf, W_attn, wa_t, W_proj, wp_t);
    k_gemm_qkv<<<dim3(18, 32), 512, 0, stream>>>(x_bf, wa_t, b_attn, Qb, Kb, Vtb, 768);
    k_attn<<<768, 256, 0, stream>>>(Qb, Kb, Vtb, attn_o);
    k_gemm_proj<<<dim3(6, 64), 256, 0, stream>>>(attn_o, wp_t, b_proj, out, 768);
}

// Round 22
// 112.955 us; speedup vs baseline: 1.2754x; 1.0100x over previous
//
#include <hip/hip_runtime.h>

typedef float f32x4 __attribute__((ext_vector_type(4)));
typedef __bf16 bf16x8 __attribute__((ext_vector_type(8)));
typedef unsigned short u16x8 __attribute__((ext_vector_type(8)));
typedef unsigned short u16x4 __attribute__((ext_vector_type(4)));

#define MFMA16(a, b, c) __builtin_amdgcn_mfma_f32_16x16x32_bf16((a), (b), (c), 0, 0, 0)

__device__ __forceinline__ unsigned short f2bf(float f) {
    __bf16 h = (__bf16)f;  // RNE
    union { __bf16 h; unsigned short u; } c; c.h = h;
    return c.u;
}

__device__ __forceinline__ void gload_lds16(const unsigned short* g, unsigned short* l) {
    __builtin_amdgcn_global_load_lds(
        (const __attribute__((address_space(1))) unsigned int*)g,
        (__attribute__((address_space(3))) unsigned int*)l, 16, 0, 0);
}

// ---- prep: weight transposes (fp32 [R][C] -> bf16 [C][R]) + x fp32->bf16 -------
__global__ void k_prepconv(const float* __restrict__ x, unsigned short* __restrict__ xb,
                           const float* __restrict__ Wa, unsigned short* __restrict__ WaT,
                           const float* __restrict__ Wp, unsigned short* __restrict__ WpT) {
    __shared__ unsigned short tile[32][33];
    const int bx = blockIdx.x, by = blockIdx.y;
    const int tx = threadIdx.x, ty = threadIdx.y;
    if (bx >= 96) {
        const int idx = (bx - 96) * 24 + by;       // 0..6143
        const int i = (idx * 256 + ty * 32 + tx) * 4;
        float4 v = *reinterpret_cast<const float4*>(x + i);
        ushort4 o;
        o.x = f2bf(v.x); o.y = f2bf(v.y); o.z = f2bf(v.z); o.w = f2bf(v.w);
        *reinterpret_cast<ushort4*>(xb + i) = o;
        return;
    }
    const int seg = (bx < 72) ? 0 : 1;
    const float* in = seg ? Wp : Wa;
    unsigned short* out = seg ? WpT : WaT;
    const int C = seg ? 768 : 2304;
    const int bx0 = (seg ? (bx - 72) : bx) * 32;
    const int by0 = by * 32;
    #pragma unroll
    for (int i = ty; i < 32; i += 8)
        tile[i][tx] = f2bf(in[(size_t)(by0 + i) * C + bx0 + tx]);
    __syncthreads();
    #pragma unroll
    for (int i = ty; i < 32; i += 8)
        out[(size_t)(bx0 + i) * 768 + by0 + tx] = tile[tx][i];
}

// ------- QKV GEMM: R16 proven config — 256x128, 512 thr, BK=64, single-buffer ---
__global__ __launch_bounds__(512) void k_gemm_qkv(
    const unsigned short* __restrict__ A,
    const unsigned short* __restrict__ Bt,
    const float* __restrict__ bias,
    unsigned short* __restrict__ Qo,
    unsigned short* __restrict__ Ko,
    unsigned short* __restrict__ Vto,
    int K)
{
    __shared__ unsigned short SM[(256 + 128) * 64];  // As(32KB) | Bs(16KB); As reused as Ts
    unsigned short* As = SM;
    unsigned short* Bs = SM + 256 * 64;
    const int nwg = gridDim.x * gridDim.y;
    const int bid0 = blockIdx.y * gridDim.x + blockIdx.x;
    const int logical = (bid0 & 7) * (nwg >> 3) + (bid0 >> 3);
    const int bm = logical / gridDim.x;
    const int bn = logical % gridDim.x;
    const int tid = threadIdx.x;
    const int w = tid >> 6, l = tid & 63;
    const int wm = w >> 1, wn = w & 1;
    const int ln = l & 15, kb = l >> 4;

    f32x4 acc[4][4];
    #pragma unroll
    for (int i = 0; i < 4; ++i)
        #pragma unroll
        for (int j = 0; j < 4; ++j)
            #pragma unroll
            for (int r = 0; r < 4; ++r) acc[i][j][r] = 0.f;

    const unsigned short* Ab = A + (size_t)(bm * 256) * K;
    const unsigned short* Bb = Bt + (size_t)(bn * 128) * K;

    const int srow = tid >> 3;   // 0..63
    const int sslot = tid & 7;
    const int csw = (sslot ^ (srow & 7)) * 8;

    for (int k0 = 0; k0 < K; k0 += 64) {
        #pragma unroll
        for (int j = 0; j < 4; ++j) {
            const int r = j * 64 + srow;
            gload_lds16(&Ab[(size_t)r * K + k0 + csw], &As[r * 64 + sslot * 8]);
        }
        #pragma unroll
        for (int j = 0; j < 2; ++j) {
            const int r = j * 64 + srow;
            gload_lds16(&Bb[(size_t)r * K + k0 + csw], &Bs[r * 64 + sslot * 8]);
        }
        __syncthreads();
        #pragma unroll
        for (int kh = 0; kh < 2; ++kh) {
            bf16x8 af[4], bfr[4];
            #pragma unroll
            for (int mt = 0; mt < 4; ++mt) {
                const int row = wm * 64 + mt * 16 + ln;
                const int slot = ((kh << 2) | kb) ^ (row & 7);
                af[mt] = *reinterpret_cast<const bf16x8*>(&As[row * 64 + slot * 8]);
            }
            #pragma unroll
            for (int nt = 0; nt < 4; ++nt) {
                const int row = wn * 64 + nt * 16 + ln;
                const int slot = ((kh << 2) | kb) ^ (row & 7);
                bfr[nt] = *reinterpret_cast<const bf16x8*>(&Bs[row * 64 + slot * 8]);
            }
            #pragma unroll
            for (int mt = 0; mt < 4; ++mt)
                #pragma unroll
                for (int nt = 0; nt < 4; ++nt)
                    acc[mt][nt] = MFMA16(af[mt], bfr[nt], acc[mt][nt]);
        }
        __syncthreads();
    }

    const float SC = 0.1803368801111204f;  // 0.125 * log2(e)

    if (bn >= 12) {
        // V section: two 128-row halves through LDS transpose (Ts = SM region),
        // then coalesced stores into Vt with sigma key-permutation.
        unsigned short* Ts = SM;  // 128(col) x 128(row-half)
        const int cl_w = wn * 64;
        #pragma unroll
        for (int hh2 = 0; hh2 < 2; ++hh2) {
            if ((wm >> 1) == hh2) {
                #pragma unroll
                for (int mt = 0; mt < 4; ++mt) {
                    #pragma unroll
                    for (int nt = 0; nt < 4; ++nt) {
                        const int cl = cl_w + nt * 16 + ln;
                        const float bv = bias[bn * 128 + cl];
                        #pragma unroll
                        for (int r = 0; r < 4; ++r) {
                            const int rl = (wm & 1) * 64 + mt * 16 + kb * 4 + r;  // 0..127
                            const int pos = cl * 128 + ((((rl >> 3) ^ (cl & 7)) << 3) | (rl & 7));
                            Ts[pos] = f2bf(acc[mt][nt][r] + bv);
                        }
                    }
                }
            }
            __syncthreads();
            {
                const int cl = tid >> 2;
                const int col = bn * 128 + cl;
                const int cc = col - 1536;
                const int hh = cc >> 6, dd = cc & 63;
                #pragma unroll
                for (int j8 = 0; j8 < 4; ++j8) {
                    const int rb = (tid & 3) * 4 + j8;
                    u16x8 val = *reinterpret_cast<const u16x8*>(&Ts[cl * 128 + ((rb ^ (cl & 7)) << 3)]);
                    const int tg = bm * 256 + hh2 * 128 + rb * 8;
                    const int bb = tg >> 11;
                    const int tloc = tg & 2047;
                    const int grp = tloc & ~31;
                    const int jj = (tloc >> 3) & 3;
                    const int tlo = grp + 8 * ((2 * jj) & 3) + 4 * (jj >> 1);
                    const int thi = grp + 8 * ((2 * jj + 1) & 3) + 4 * (jj >> 1);
                    unsigned short* basep = &Vto[((size_t)((bb * 12 + hh) * 64 + dd)) * 2048];
                    *reinterpret_cast<u16x4*>(basep + tlo) =
                        __builtin_shufflevector(val, val, 0, 1, 2, 3);
                    *reinterpret_cast<u16x4*>(basep + thi) =
                        __builtin_shufflevector(val, val, 4, 5, 6, 7);
                }
            }
            __syncthreads();
        }
        return;
    }

    #pragma unroll
    for (int mt = 0; mt < 4; ++mt) {
        #pragma unroll
        for (int nt = 0; nt < 4; ++nt) {
            const int col = bn * 128 + wn * 64 + nt * 16 + ln;
            #pragma unroll
            for (int r = 0; r < 4; ++r) {
                const int row = bm * 256 + wm * 64 + mt * 16 + kb * 4 + r;
                float v = acc[mt][nt][r] + bias[col];
                int cc = col >= 768 ? col - 768 : col;
                int h = cc >> 6, d = cc & 63;
                int b = row >> 11, t = row & 2047;
                if (col < 768)
                    Qo[((size_t)((b * 12 + h) * 2048 + t)) * 64 + d] = f2bf(v * SC);
                else
                    Ko[((size_t)((b * 12 + h) * 2048 + t)) * 64 + d] = f2bf(v);
            }
        }
    }
}

// ------- proj GEMM: R16 proven config — 128x128 block, 256 thr, BK=64, 1-buf ----
__global__ __launch_bounds__(256) void k_gemm_proj(
    const unsigned short* __restrict__ A,
    const unsigned short* __restrict__ Bt,
    const float* __restrict__ bias,
    float* __restrict__ Co,
    int K)
{
    constexpr int BM = 128;
    __shared__ unsigned short SM[(BM + 128) * 64];
    unsigned short* As = SM;
    unsigned short* Bs = SM + BM * 64;
    const int nwg = gridDim.x * gridDim.y;
    const int bid0 = blockIdx.y * gridDim.x + blockIdx.x;
    const int logical = (bid0 & 7) * (nwg >> 3) + (bid0 >> 3);
    const int bm = logical / gridDim.x;
    const int bn = logical % gridDim.x;
    const int tid = threadIdx.x;
    const int w = tid >> 6, l = tid & 63;
    const int wm = w >> 1, wn = w & 1;
    const int ln = l & 15, kb = l >> 4;

    f32x4 acc[4][4];
    #pragma unroll
    for (int i = 0; i < 4; ++i)
        #pragma unroll
        for (int j = 0; j < 4; ++j)
            #pragma unroll
            for (int r = 0; r < 4; ++r) acc[i][j][r] = 0.f;

    const unsigned short* Ab = A + (size_t)(bm * BM) * K;
    const unsigned short* Bb = Bt + (size_t)(bn * 128) * K;

    const int srow = tid >> 3;
    const int sslot = tid & 7;
    const int csw = (sslot ^ (srow & 7)) * 8;

    for (int k0 = 0; k0 < K; k0 += 64) {
        #pragma unroll
        for (int j = 0; j < 4; ++j) {
            const int r = j * 32 + srow;
            gload_lds16(&Ab[(size_t)r * K + k0 + csw], &As[r * 64 + sslot * 8]);
        }
        #pragma unroll
        for (int j = 0; j < 4; ++j) {
            const int r = j * 32 + srow;
            gload_lds16(&Bb[(size_t)r * K + k0 + csw], &Bs[r * 64 + sslot * 8]);
        }
        __syncthreads();
        #pragma unroll
        for (int kh = 0; kh < 2; ++kh) {
            bf16x8 af[4], bfr[4];
            #pragma unroll
            for (int mt = 0; mt < 4; ++mt) {
                const int row = wm * 64 + mt * 16 + ln;
                const int slot = ((kh << 2) | kb) ^ (row & 7);
                af[mt] = *reinterpret_cast<const bf16x8*>(&As[row * 64 + slot * 8]);
            }
            #pragma unroll
            for (int nt = 0; nt < 4; ++nt) {
                const int row = wn * 64 + nt * 16 + ln;
                const int slot = ((kh << 2) | kb) ^ (row & 7);
                bfr[nt] = *reinterpret_cast<const bf16x8*>(&Bs[row * 64 + slot * 8]);
            }
            #pragma unroll
            for (int mt = 0; mt < 4; ++mt)
                #pragma unroll
                for (int nt = 0; nt < 4; ++nt)
                    acc[mt][nt] = MFMA16(af[mt], bfr[nt], acc[mt][nt]);
        }
        __syncthreads();
    }

    #pragma unroll
    for (int mt = 0; mt < 4; ++mt) {
        #pragma unroll
        for (int nt = 0; nt < 4; ++nt) {
            const int col = bn * 128 + wn * 64 + nt * 16 + ln;
            #pragma unroll
            for (int r = 0; r < 4; ++r) {
                const int row = bm * BM + wm * 64 + mt * 16 + kb * 4 + r;
                Co[(size_t)row * 768 + col] = acc[mt][nt][r] + bias[col];
            }
        }
    }
}

// ---- flash attention v13c: R14 winner + T5 setprio around MFMA clusters ---------
// (blocks independent -> m191-positive regime; never A/B'd on the dieted kernel)
__global__ __launch_bounds__(256) void k_attn(
    const unsigned short* __restrict__ Q,   // [BH][T][64] (pre-scaled)
    const unsigned short* __restrict__ Kk,  // [BH][T][64]
    const unsigned short* __restrict__ Vt,  // [BH][64][T'] (sigma-permuted keys)
    unsigned short* __restrict__ Oo)        // [B][T][768] bf16
{
    __shared__ unsigned short SMEM[4 * 4096];  // Ks0|Ks1|Vs0|Vs1 (32KB)
    const int bid0 = blockIdx.x;
    const int xcd = bid0 & 7;
    const int loc = bid0 >> 3;
    const int qb = 15 - (loc / 6);
    const int bh = xcd * 6 + (loc % 6);
    const int tid = threadIdx.x;
    const int w = tid >> 6, l = tid & 63;
    const int ln = l & 15, kb = l >> 4;
    const int kbq = kb * 4;
    const int b = bh / 12, h = bh - b * 12;
    const int q0w = qb * 128 + w * 32;

    const unsigned short* Qb = Q + (size_t)bh * 2048 * 64;
    const unsigned short* Kb = Kk + (size_t)bh * 2048 * 64;
    const unsigned short* Vb = Vt + (size_t)bh * 64 * 2048;

    bf16x8 qf[2][2];
    #pragma unroll
    for (int qn = 0; qn < 2; ++qn) {
        const unsigned short* qr = &Qb[(size_t)(q0w + qn * 16 + ln) * 64 + kb * 8];
        qf[qn][0] = *reinterpret_cast<const bf16x8*>(qr);
        qf[qn][1] = *reinterpret_cast<const bf16x8*>(qr + 32);
    }

    bf16x8 vones;
    #pragma unroll
    for (int e = 0; e < 8; ++e) vones[e] = (__bf16)1.0f;
    const f32x4 fzero = {0.f, 0.f, 0.f, 0.f};

    f32x4 oaccT[2][4];
    f32x4 den[2];
    #pragma unroll
    for (int qn = 0; qn < 2; ++qn) {
        #pragma unroll
        for (int r = 0; r < 4; ++r) den[qn][r] = 0.f;
        #pragma unroll
        for (int dt = 0; dt < 4; ++dt)
            #pragma unroll
            for (int r = 0; r < 4; ++r) oaccT[qn][dt][r] = 0.f;
    }

    const int lb = ln & 7;
    const int aR0 = ln * 64 + (kb ^ lb) * 8;
    const int aR1 = ln * 64 + ((4 | kb) ^ lb) * 8;

    const int srow = tid >> 3;
    const int sslot = tid & 7;
    const int csw = (sslot ^ (srow & 7)) * 8;
    const int lastkt = (q0w + 31) >> 6;

    #define STAGE(kt_, buf_)                                                        \
        {                                                                           \
            const int kb_ = (kt_) * 64;                                             \
            _Pragma("unroll")                                                       \
            for (int j = 0; j < 2; ++j) {                                           \
                const int r = j * 32 + srow;                                        \
                gload_lds16(&Kb[(size_t)(kb_ + r) * 64 + csw],                      \
                            &SMEM[(buf_) * 4096 + r * 64 + sslot * 8]);             \
                gload_lds16(&Vb[(size_t)r * 2048 + kb_ + csw],                      \
                            &SMEM[8192 + (buf_) * 4096 + r * 64 + sslot * 8]);      \
            }                                                                       \
        }

    #define COMPUTE(kt_, BUF)                                                       \
        if ((kt_) <= lastkt) {                                                      \
            bf16x8 kf[4][2];                                                        \
            _Pragma("unroll")                                                       \
            for (int km = 0; km < 4; ++km) {                                        \
                kf[km][0] = *reinterpret_cast<const bf16x8*>(                       \
                    &SMEM[(BUF) * 4096 + km * 1024 + aR0]);                         \
                kf[km][1] = *reinterpret_cast<const bf16x8*>(                       \
                    &SMEM[(BUF) * 4096 + km * 1024 + aR1]);                         \
            }                                                                       \
            f32x4 st[4][2];                                                         \
            __builtin_amdgcn_s_setprio(1);                                          \
            _Pragma("unroll")                                                       \
            for (int km = 0; km < 4; ++km)                                          \
                _Pragma("unroll")                                                   \
                for (int qn = 0; qn < 2; ++qn) {                                    \
                    st[km][qn] = MFMA16(kf[km][0], qf[qn][0], fzero);               \
                    st[km][qn] = MFMA16(kf[km][1], qf[qn][1], st[km][qn]);          \
                }                                                                   \
            __builtin_amdgcn_s_setprio(0);                                          \
            bf16x8 vf[4][2];                                                        \
            _Pragma("unroll")                                                       \
            for (int dt = 0; dt < 4; ++dt) {                                        \
                vf[dt][0] = *reinterpret_cast<const bf16x8*>(                       \
                    &SMEM[8192 + (BUF) * 4096 + dt * 1024 + aR0]);                  \
                vf[dt][1] = *reinterpret_cast<const bf16x8*>(                       \
                    &SMEM[8192 + (BUF) * 4096 + dt * 1024 + aR1]);                  \
            }                                                                       \
            if ((kt_) == lastkt) {                                                  \
                const int kbase_ = (kt_) * 64;                                      \
                _Pragma("unroll")                                                   \
                for (int qn = 0; qn < 2; ++qn) {                                    \
                    const int qrow = q0w + qn * 16 + ln;                            \
                    _Pragma("unroll")                                               \
                    for (int km = 0; km < 4; ++km)                                  \
                        _Pragma("unroll")                                           \
                        for (int r = 0; r < 4; ++r) {                               \
                            float sv = st[km][qn][r];                               \
                            const int key = kbase_ + km * 16 + kbq + r;             \
                            sv = (key <= qrow) ? sv : -1e30f;                       \
                            st[km][qn][r] = __builtin_amdgcn_exp2f(sv);             \
                        }                                                           \
                }                                                                   \
            } else {                                                                \
                _Pragma("unroll")                                                   \
                for (int qn = 0; qn < 2; ++qn)                                      \
                    _Pragma("unroll")                                               \
                    for (int km = 0; km < 4; ++km)                                  \
                        _Pragma("unroll")                                           \
                        for (int r = 0; r < 4; ++r)                                 \
                            st[km][qn][r] =                                         \
                                __builtin_amdgcn_exp2f(st[km][qn][r]);              \
            }                                                                       \
            bf16x8 pa[2][2];                                                        \
            _Pragma("unroll")                                                       \
            for (int qn = 0; qn < 2; ++qn)                                          \
                _Pragma("unroll")                                                   \
                for (int kh = 0; kh < 2; ++kh) {                                    \
                    bf16x8 t;                                                       \
                    _Pragma("unroll")                                               \
                    for (int r = 0; r < 4; ++r) {                                   \
                        t[r]     = (__bf16)st[2 * kh][qn][r];                       \
                        t[r + 4] = (__bf16)st[2 * kh + 1][qn][r];                   \
                    }                                                               \
                    pa[qn][kh] = t;                                                 \
                }                                                                   \
            __builtin_amdgcn_s_setprio(1);                                          \
            _Pragma("unroll")                                                       \
            for (int qn = 0; qn < 2; ++qn) {                                        \
                _Pragma("unroll")                                                   \
                for (int dt = 0; dt < 4; ++dt) {                                    \
                    oaccT[qn][dt] = MFMA16(pa[qn][0], vf[dt][0], oaccT[qn][dt]);    \
                    oaccT[qn][dt] = MFMA16(pa[qn][1], vf[dt][1], oaccT[qn][dt]);    \
                }                                                                   \
                den[qn] = MFMA16(pa[qn][0], vones, den[qn]);                        \
                den[qn] = MFMA16(pa[qn][1], vones, den[qn]);                        \
            }                                                                       \
            __builtin_amdgcn_s_setprio(0);                                          \
        }

    STAGE(0, 0);

    for (int s = 0; s <= qb; ++s) {
        const int ktA = 2 * s;
        const int ktB = 2 * s + 1;
        __syncthreads();
        STAGE(ktB, 1);
        COMPUTE(ktA, 0);
        __syncthreads();
        if (s < qb) STAGE(ktA + 2, 0);
        COMPUTE(ktB, 1);
    }

    #pragma unroll
    for (int qn = 0; qn < 2; ++qn) {
        #pragma unroll
        for (int r = 0; r < 4; ++r) {
            const float inv = 1.0f / den[qn][r];
            const int t = q0w + qn * 16 + kbq + r;
            #pragma unroll
            for (int dt = 0; dt < 4; ++dt)
                Oo[((size_t)(b * 2048 + t)) * 768 + h * 64 + dt * 16 + ln] =
                    f2bf(oaccT[qn][dt][r] * inv);
        }
    }
    #undef STAGE
    #undef COMPUTE
}

extern "C" void kernel_launch(void* const* d_in, const int* in_sizes, int n_in,
                              void* d_out, int out_size, void* d_ws, size_t ws_size,
                              hipStream_t stream) {
    const float* x      = (const float*)d_in[0];
    const float* W_attn = (const float*)d_in[1];
    const float* b_attn = (const float*)d_in[2];
    const float* W_proj = (const float*)d_in[3];
    const float* b_proj = (const float*)d_in[4];
    float* out = (float*)d_out;

    char* ws = (char*)d_ws;
    const size_t SZ_X  = (size_t)8192 * 768 * 2;
    const size_t SZ_WA = (size_t)2304 * 768 * 2;
    const size_t SZ_WP = (size_t)768 * 768 * 2;
    const size_t SZ_T  = (size_t)8192 * 768 * 2;

    unsigned short* x_bf = (unsigned short*)(ws);
    unsigned short* wa_t = (unsigned short*)(ws + SZ_X);
    unsigned short* wp_t = (unsigned short*)(ws + SZ_X + SZ_WA);
    unsigned short* Qb   = (unsigned short*)(ws + SZ_X + SZ_WA + SZ_WP);
    unsigned short* Kb   = (unsigned short*)(ws + SZ_X + SZ_WA + SZ_WP + SZ_T);
    unsigned short* Vtb  = (unsigned short*)(ws + SZ_X + SZ_WA + SZ_WP + 2 * SZ_T);
    unsigned short* attn_o = x_bf;  // x_bf dead after QKV GEMM; reuse

    k_prepconv<<<dim3(96 + 256, 24), dim3(32, 8), 0, stream>>>(x, x_bf, W_attn, wa_t, W_proj, wp_t);
    k_gemm_qkv<<<dim3(18, 32), 512, 0, stream>>>(x_bf, wa_t, b_attn, Qb, Kb, Vtb, 768);
    k_attn<<<768, 256, 0, stream>>>(Qb, Kb, Vtb, attn_o);
    k_gemm_proj<<<dim3(6, 64), 256, 0, stream>>>(attn_o, wp_t, b_proj, out, 768);
}